// Round 7
// baseline (248.169 us; speedup 1.0000x reference)
//
#include <hip/hip_runtime.h>
#include <hip/hip_bf16.h>

// LinearAttention: B=8, C=512, L=4096, HEADS=8, dim_head=64, hidden=512
// R12: GEMM occupancy play: BK 64->32 halves LDS (32 KiB) -> 4 blocks/CU
//      (2x independent streams/CU to hide staging-miss latency, the measured
//      ~85% per-block stall). Same 128^2 tile + counted-vmcnt discipline.
//      Swizzle re-derived for 64B rows (grp ^ row&3; 2-way = free).
// Pipeline: prep_all; gemm_p<1>(exp-k,v); ctx; w2; gemm_p<3>(W3); gemm_p<2>(out).

typedef __bf16 bf16x8 __attribute__((ext_vector_type(8)));
typedef __bf16 bf16x4 __attribute__((ext_vector_type(4)));
typedef float  f32x4  __attribute__((ext_vector_type(4)));

#define B_  8
#define L_  4096
#define C_  512

#define GLD_LDS16(g, l)                                             \
    __builtin_amdgcn_global_load_lds(                               \
        (const __attribute__((address_space(1))) void*)(g),         \
        (__attribute__((address_space(3))) void*)(l), 16, 0, 0)

#define FENCE asm volatile("" ::: "memory")
#define BAR   do { FENCE; __builtin_amdgcn_s_barrier(); FENCE; } while (0)
#define DRAIN_LGKM asm volatile("s_waitcnt lgkmcnt(0)" ::: "memory")
#define WAIT_VM(N) asm volatile("s_waitcnt vmcnt(" #N ")" ::: "memory")

// ---------------- prep_all: x-transpose+cvt | wkv cvt | WqT ----------------
__global__ __launch_bounds__(256) void prep_all(const float* __restrict__ x,
                                                __hip_bfloat16* __restrict__ xt,
                                                const float* __restrict__ wqkv_f,
                                                __hip_bfloat16* __restrict__ wkv_b,
                                                __hip_bfloat16* __restrict__ wqT) {
    __shared__ float tile[64 * 133];
    int blk = blockIdx.x;
    int t = threadIdx.x;
    if (blk < 2048) {
        // transpose fp32 x[b][C][L] -> bf16 xt[b][L][C]; 64c x 128l tile
        int b = blk >> 8, rem = blk & 255;
        int l0 = (rem & 31) * 128, c0 = (rem >> 5) * 64;
        const float* xp = x + ((size_t)b * C_ + c0) * L_ + l0;
#pragma unroll
        for (int p = 0; p < 8; p++) {
            int i = p * 8 + (t >> 5);
            int j = (t & 31) * 4;
            float4 vv = *(const float4*)(xp + (size_t)i * L_ + j);
            *(float4*)&tile[i * 133 + j] = vv;
        }
        __syncthreads();
        unsigned short* xo = (unsigned short*)xt + ((size_t)b * L_ + l0) * C_ + c0;
        int cg8 = (t & 7) * 8;
#pragma unroll
        for (int qq = 0; qq < 4; qq++) {
            int l = qq * 32 + (t >> 3);
            bf16x8 ov;
#pragma unroll
            for (int k = 0; k < 8; k++) ov[k] = (__bf16)tile[(cg8 + k) * 133 + l];
            *(bf16x8*)(xo + (size_t)l * C_ + cg8) = ov;
        }
    } else if (blk < 4096) {
        int i = (blk - 2048) * 256 + t;  // 1024*512 elements (w_qkv rows 512..1535)
        wkv_b[i] = __float2bfloat16(wqkv_f[512 * 512 + i]);
    } else {
        // wqT[c][c'] = w_qkv[c'][c] (q-part rows 0..511), bf16
        int tb = blk - 4096;
        int r0 = (tb >> 4) * 32, c0 = (tb & 15) * 32;
        int tx = t & 31, ty = t >> 5;
        for (int r = 0; r < 32; r += 8)
            tile[(ty + r) * 33 + tx] = wqkv_f[(size_t)(r0 + ty + r) * 512 + c0 + tx];
        __syncthreads();
        for (int r = 0; r < 32; r += 8)
            wqT[(size_t)(c0 + ty + r) * 512 + r0 + tx] = __float2bfloat16(tile[tx * 33 + ty + r]);
    }
}

// ---------------- pipelined 128^2 GEMM, BK=32, 4 blocks/CU ----------------
// C[M][N] = A[M][K] * Bt[N][K]^T.  BM=BN=128, BK=32, 256 thr (2x2 waves),
// per-wave C = 64x64.  LDS 32 KiB -> 4 blocks/CU (the latency-hiding lever).
// LDS rows 64B = 4x16B groups; group g of row r holds k-group g^(r&3).
// Staging: 1 GLD call = 256 lanes x 16B = 64 rows; lane -> (row=lane>>2, grp=lane&3).
// Frag read: group (q4 ^ (l16&3)); per-8-lane phase -> 4 spans x 2 lanes = 2-way (free).
// Loop kt: ds_read frags(buf[kt&1]); lgkm-drain; BAR; stage kt+2 -> buf[kt&1];
//          16 MFMA; vmcnt(4) [kt+1 complete, kt+2 in flight]; BAR.
// MODE 1: M=1024: rows 0-511 -> kb as exp(val) bf16, 512-1023 -> vb.
// MODE 2: fp32 out + bias.  MODE 3: bf16 out.
template <int MODE>
__global__ __launch_bounds__(256, 4) void gemm_p(
    const __hip_bfloat16* __restrict__ A, const __hip_bfloat16* __restrict__ Bt,
    size_t strideA, size_t strideB, int M, int N, int K,
    __hip_bfloat16* __restrict__ kb, __hip_bfloat16* __restrict__ vb,
    __hip_bfloat16* __restrict__ obf,
    float* __restrict__ outb, const float* __restrict__ bias) {
    __shared__ alignas(16) unsigned short sA[2][128 * 32];  // 8 KiB x2
    __shared__ alignas(16) unsigned short sB[2][128 * 32];  // 8 KiB x2

    int b = blockIdx.z;
    int m0 = blockIdx.y * 128, n0 = blockIdx.x * 128;
    const __hip_bfloat16* Ab = A + strideA * (size_t)b;
    const __hip_bfloat16* Bb = Bt + strideB * (size_t)b;

    int t = threadIdx.x;
    int lane = t & 63, wv = t >> 6;
    int l16 = lane & 15, q4 = lane >> 4;
    int wr = (wv >> 1) * 64, wc = (wv & 1) * 64;

    // staging: lane -> (row = lane>>2 within 64-row chunk, grp = lane&3)
    int srow = lane >> 2;
    int swz  = ((lane & 3) ^ (srow & 3)) * 8;  // k-offset (elems) within 32-block

    const __hip_bfloat16* gA[2];
    const __hip_bfloat16* gB[2];
    unsigned ldoff[2];
#pragma unroll
    for (int c = 0; c < 2; c++) {
        int lr = c * 64 + wv * 16 + srow;  // local row 0..127
        gA[c] = Ab + (size_t)(m0 + lr) * K + swz;
        gB[c] = Bb + (size_t)(n0 + lr) * K + swz;
        ldoff[c] = (unsigned)(c * 64 + wv * 16) * 32;
    }

    int gsel = (q4 ^ (l16 & 3)) * 8;
    unsigned rA = (unsigned)(wr + l16) * 32;
    unsigned rB = (unsigned)(wc + l16) * 32;
    const int NKT = K >> 5;  // 16

    f32x4 acc[4][4] = {};
    bf16x8 aF[4], bF[4];

    // prologue: stage tile0 -> buf0, tile1 -> buf1; leave tile1 (4) in flight
#pragma unroll
    for (int c = 0; c < 2; c++) {
        GLD_LDS16(gA[c], &sA[0][ldoff[c]]);
        GLD_LDS16(gB[c], &sB[0][ldoff[c]]);
    }
#pragma unroll
    for (int c = 0; c < 2; c++) {
        GLD_LDS16(gA[c] + 32, &sA[1][ldoff[c]]);
        GLD_LDS16(gB[c] + 32, &sB[1][ldoff[c]]);
    }
    WAIT_VM(4);
    BAR;

#pragma unroll 1
    for (int kt = 0; kt < NKT; ++kt) {
        int cur = kt & 1;
        const unsigned short* As_b = sA[cur];
        const unsigned short* Bs_b = sB[cur];
        bool st2 = (kt + 2) < NKT;

        // ds_read all frags of this K-tile
#pragma unroll
        for (int i = 0; i < 4; i++) aF[i] = *(const bf16x8*)&As_b[rA + i * 512 + gsel];
#pragma unroll
        for (int j = 0; j < 4; j++) bF[j] = *(const bf16x8*)&Bs_b[rB + j * 512 + gsel];
        DRAIN_LGKM;   // this wave's reads complete
        BAR;          // all waves done reading buf[cur] -> safe to overwrite

        if (st2) {
            int ko = (kt + 2) << 5;
#pragma unroll
            for (int c = 0; c < 2; c++) {
                GLD_LDS16(gA[c] + ko, &sA[cur][ldoff[c]]);
                GLD_LDS16(gB[c] + ko, &sB[cur][ldoff[c]]);
            }
        }
        __builtin_amdgcn_s_setprio(1);
#pragma unroll
        for (int i = 0; i < 4; i++)
#pragma unroll
            for (int j = 0; j < 4; j++)
                acc[i][j] = __builtin_amdgcn_mfma_f32_16x16x32_bf16(aF[i], bF[j], acc[i][j], 0, 0, 0);
        __builtin_amdgcn_s_setprio(0);
        if (st2) { WAIT_VM(4); } else { WAIT_VM(0); }  // kt+1 complete; kt+2 stays in flight
        BAR;
    }

    // epilogue: D row = q4*4 + r (within 16), col = l16
#pragma unroll
    for (int i = 0; i < 4; i++)
#pragma unroll
        for (int j = 0; j < 4; j++)
#pragma unroll
            for (int r = 0; r < 4; r++) {
                int row = m0 + wr + i * 16 + q4 * 4 + r;
                int col = n0 + wc + j * 16 + l16;
                float val = acc[i][j][r];
                if (MODE == 1) {
                    bool isk = (m0 < 512);  // 128-tile never straddles k/v halves
                    __hip_bfloat16* dst = isk ? kb : vb;
                    if (isk) val = __expf(val);  // store exp(k): ctx needs only exp
                    dst[((size_t)b * 512 + (row & 511)) * (size_t)N + col] = __float2bfloat16(val);
                } else if (MODE == 3) {
                    obf[((size_t)b * 512 + row) * (size_t)N + col] = __float2bfloat16(val);
                } else {
                    outb[((size_t)b * M + row) * (size_t)N + col] = val + bias[row];
                }
            }
}

// ---------------- ctx partials: ctxp[kc][bh][d][e] = sum_{n in kc} ek[d,n]*v[e,n]
//                  Sp[kc][bh][d] = sum ek[d,n].  d split across 2 blocks (dh):
//                  grid (16 = kc*2+dh, 8 h, 8 b) = 1024 blocks.
__global__ __launch_bounds__(256) void ctx_kernel(const __hip_bfloat16* __restrict__ ek,
                                                  const __hip_bfloat16* __restrict__ v,
                                                  float* __restrict__ ctxp,
                                                  float* __restrict__ Sp) {
    int bx = blockIdx.x;
    int kc = bx >> 1, dh = bx & 1;
    int h = blockIdx.y, b = blockIdx.z;
    int t = threadIdx.x, lane = t & 63, wv = t >> 6;
    int l16 = lane & 15, q4 = lane >> 4;
    const __hip_bfloat16* ka = ek + ((size_t)b * 512 + h * 64 + dh * 32) * L_;
    const __hip_bfloat16* va = v + ((size_t)b * 512 + h * 64) * L_;

    f32x4 acc[2][4] = {};
    float ps[2] = {0.f, 0.f};
    int nbase = kc * 512 + wv * 128;
#pragma unroll
    for (int s = 0; s < 4; s++) {
        int n = nbase + s * 32 + q4 * 8;
        bf16x8 af[2], bfr[4];
#pragma unroll
        for (int i = 0; i < 2; i++) {
            af[i] = *(const bf16x8*)(ka + (size_t)(i * 16 + l16) * L_ + n);
#pragma unroll
            for (int e = 0; e < 8; e++) ps[i] += (float)af[i][e];
        }
#pragma unroll
        for (int j = 0; j < 4; j++)
            bfr[j] = *(const bf16x8*)(va + (size_t)(j * 16 + l16) * L_ + n);
#pragma unroll
        for (int i = 0; i < 2; i++)
#pragma unroll
            for (int j = 0; j < 4; j++)
                acc[i][j] = __builtin_amdgcn_mfma_f32_16x16x32_bf16(af[i], bfr[j], acc[i][j], 0, 0, 0);
    }

    __shared__ float sred[4][32];
#pragma unroll
    for (int i = 0; i < 2; i++) {
        ps[i] += __shfl_xor(ps[i], 16, 64);
        ps[i] += __shfl_xor(ps[i], 32, 64);
    }
    if (q4 == 0) {
#pragma unroll
        for (int i = 0; i < 2; i++) sred[wv][i * 16 + l16] = ps[i];
    }

    __shared__ float cbuf[2048];
    __syncthreads();
    for (int w = 0; w < 4; w++) {
        if (wv == w) {
#pragma unroll
            for (int i = 0; i < 2; i++)
#pragma unroll
                for (int j = 0; j < 4; j++)
#pragma unroll
                    for (int r = 0; r < 4; r++) {
                        int mm = i * 16 + q4 * 4 + r, nn = j * 16 + l16;
                        float pv = acc[i][j][r];
                        if (w == 0) cbuf[mm * 64 + nn] = pv;
                        else        cbuf[mm * 64 + nn] += pv;
                    }
        }
        __syncthreads();
    }
    float* cg = ctxp + ((size_t)kc * 64 + b * 8 + h) * 4096 + dh * 2048;
    for (int i = t; i < 2048; i += 256) cg[i] = cbuf[i];
    if (t < 32)
        Sp[((size_t)kc * 64 + b * 8 + h) * 64 + dh * 32 + t] =
            sred[0][t] + sred[1][t] + sred[2][t] + sred[3][t];
}

// ---------------- w2[b][o][h*64+d] = sum_e w_out[o][h*64+e] * ctx[d][e]/S[d] ----------------
__global__ __launch_bounds__(256) void w2_kernel(const float* __restrict__ wout,
                                                 const float* __restrict__ ctxp,
                                                 const float* __restrict__ Sp,
                                                 __hip_bfloat16* __restrict__ w2) {
    int ob = blockIdx.x, h = blockIdx.y, b = blockIdx.z;
    __shared__ float cT[64 * 65];  // [e][d], pre-scaled by 1/S[d]
    __shared__ float wT[64 * 65];  // [e][ol]
    __shared__ float Sinv[64];
    int t = threadIdx.x;
    const size_t SL = (size_t)64 * 4096;  // ctxp slice stride (floats)
    const float* cg = ctxp + ((size_t)b * 8 + h) * 4096;
    if (t < 64) {
        const float* sg = Sp + ((size_t)b * 8 + h) * 64;
        float S = 0.f;
#pragma unroll
        for (int s = 0; s < 8; s++) S += sg[(size_t)s * 64 * 64 + t];
        Sinv[t] = 1.0f / S;
    }
    __syncthreads();
#pragma unroll
    for (int it = 0; it < 4; ++it) {
        int i0 = (t + it * 256) * 4;
        int d = i0 >> 6, e0 = i0 & 63;
        float4 s4 = {0.f, 0.f, 0.f, 0.f};
#pragma unroll
        for (int sl = 0; sl < 8; sl++) {
            float4 vv = *(const float4*)&cg[(size_t)sl * SL + i0];
            s4.x += vv.x; s4.y += vv.y; s4.z += vv.z; s4.w += vv.w;
        }
        float si = Sinv[d];
        float4 wv4 = *(const float4*)&wout[(size_t)(ob * 64 + d) * 512 + h * 64 + e0];
        cT[(e0 + 0) * 65 + d] = s4.x * si;
        cT[(e0 + 1) * 65 + d] = s4.y * si;
        cT[(e0 + 2) * 65 + d] = s4.z * si;
        cT[(e0 + 3) * 65 + d] = s4.w * si;
        wT[(e0 + 0) * 65 + d] = wv4.x;
        wT[(e0 + 1) * 65 + d] = wv4.y;
        wT[(e0 + 2) * 65 + d] = wv4.z;
        wT[(e0 + 3) * 65 + d] = wv4.w;
    }
    __syncthreads();
    int ol = t >> 2;
    int db = (t & 3) * 16;
    unsigned short* w2p = (unsigned short*)w2 + ((size_t)b * 512 + ob * 64 + ol) * 512 + h * 64;
    for (int g = 0; g < 4; g++) {
        int d0 = db + g * 4;
        float s0 = 0.f, s1 = 0.f, s2 = 0.f, s3 = 0.f;
#pragma unroll
        for (int e = 0; e < 64; e++) {
            float w = wT[e * 65 + ol];
            s0 += w * cT[e * 65 + d0];
            s1 += w * cT[e * 65 + d0 + 1];
            s2 += w * cT[e * 65 + d0 + 2];
            s3 += w * cT[e * 65 + d0 + 3];
        }
        bf16x4 ov;
        ov[0] = (__bf16)s0; ov[1] = (__bf16)s1; ov[2] = (__bf16)s2; ov[3] = (__bf16)s3;
        *(bf16x4*)(w2p + d0) = ov;
    }
}

// ---------------- launch ----------------
extern "C" void kernel_launch(void* const* d_in, const int* in_sizes, int n_in,
                              void* d_out, int out_size, void* d_ws, size_t ws_size,
                              hipStream_t stream) {
    const float* x     = (const float*)d_in[0];
    const float* w_qkv = (const float*)d_in[1];
    const float* w_out = (const float*)d_in[2];
    const float* b_out = (const float*)d_in[3];
    float* out = (float*)d_out;
    char* ws = (char*)d_ws;

    const size_t QKV = (size_t)B_ * 512 * L_;
    size_t off_xt   = 0;                                      // bf16 [b][L][C]  32 MiB
    size_t off_wkv  = off_xt + (size_t)B_ * L_ * C_ * 2;      // bf16 1024x512    1 MiB
    size_t off_wqT  = off_wkv + (size_t)1024 * 512 * 2;       // bf16 512x512   0.5 MiB
    size_t off_k    = off_wqT + (size_t)512 * 512 * 2;        // bf16 exp(k)     32 MiB
    size_t off_v    = off_k + QKV * 2;                        // bf16            32 MiB
    size_t off_ctxp = off_v + QKV * 2;                        // fp32 8sl*64bh*4096 8 MiB
    size_t off_Sp   = off_ctxp + (size_t)8 * 64 * 4096 * 4;   // fp32 8sl*64bh*64 128 KiB
    // w2 / W3 overlay the dead kb region (kb fully consumed by ctx before w2 writes)
    size_t off_w2   = off_k;                                  // bf16 8x512x512   4 MiB
    size_t off_w3   = off_k + (size_t)B_ * 512 * 512 * 2;     // bf16             4 MiB

    __hip_bfloat16* xt   = (__hip_bfloat16*)(ws + off_xt);
    __hip_bfloat16* wkvb = (__hip_bfloat16*)(ws + off_wkv);
    __hip_bfloat16* wqT  = (__hip_bfloat16*)(ws + off_wqT);
    __hip_bfloat16* kb   = (__hip_bfloat16*)(ws + off_k);
    __hip_bfloat16* vb   = (__hip_bfloat16*)(ws + off_v);
    float*          ctxp = (float*)(ws + off_ctxp);
    float*          Sp   = (float*)(ws + off_Sp);
    __hip_bfloat16* w2   = (__hip_bfloat16*)(ws + off_w2);
    __hip_bfloat16* W3   = (__hip_bfloat16*)(ws + off_w3);

    prep_all<<<4352, 256, 0, stream>>>(x, xt, w_qkv, wkvb, wqT);

    // ek,v = Wkv @ x  (M=1024, N=4096, K=512 per batch); k stored as exp(k)
    gemm_p<1><<<dim3(L_ / 128, 1024 / 128, B_), 256, 0, stream>>>(
        wkvb, xt, 0, (size_t)L_ * C_, 1024, L_, 512, kb, vb, nullptr, nullptr, nullptr);

    // ctx partials + row sums (kc=8 x dh=2, 1024 blocks)
    ctx_kernel<<<dim3(16, 8, B_), 256, 0, stream>>>(kb, vb, ctxp, Sp);

    w2_kernel<<<dim3(8, 8, B_), 256, 0, stream>>>(w_out, ctxp, Sp, w2);

    // W3[b] = w2[b] @ Wq   (M=512, N=512, K=512) — bf16 out
    gemm_p<3><<<dim3(512 / 128, 512 / 128, B_), 256, 0, stream>>>(
        w2, wqT, (size_t)512 * 512, 0, 512, 512, 512, nullptr, nullptr, W3, nullptr, nullptr);

    // out = W3[b] @ x[b] + b_out   (M=512, N=4096, K=512)
    gemm_p<2><<<dim3(L_ / 128, 512 / 128, B_), 256, 0, stream>>>(
        W3, xt, (size_t)512 * 512, (size_t)L_ * C_, 512, L_, 512, nullptr, nullptr, nullptr, out, b_out);
}

// Round 8
// 231.775 us; speedup vs baseline: 1.0707x; 1.0707x over previous
//
#include <hip/hip_runtime.h>
#include <hip/hip_bf16.h>

// LinearAttention: B=8, C=512, L=4096, HEADS=8, dim_head=64, hidden=512
// R13: fused kv-GEMM + softmax-context, reduction done right:
//   R8's verified grid/main-loop/tail (2048 blocks = 32 n-tiles x 8 h x 8 b)
//   + R9's verified LDS row-sum + PLAIN per-slice partial stores (no atomics).
//   kv never materialized (-64MB write, -64MB read). ctxred sums 32 slices.
//   gemm_p restored to R11 BK=64 (R12's BK=32 regressed: +conflicts, +barriers).
// Pipeline: prep_all; gemm_kv -> ctxp,Sp; ctxred -> ctxs; w2; gemm_p<3>(W3); gemm_p<2>(out).

typedef __bf16 bf16x8 __attribute__((ext_vector_type(8)));
typedef __bf16 bf16x4 __attribute__((ext_vector_type(4)));
typedef float  f32x4  __attribute__((ext_vector_type(4)));

#define B_  8
#define L_  4096
#define C_  512

#define GLD_LDS16(g, l)                                             \
    __builtin_amdgcn_global_load_lds(                               \
        (const __attribute__((address_space(1))) void*)(g),         \
        (__attribute__((address_space(3))) void*)(l), 16, 0, 0)

#define FENCE asm volatile("" ::: "memory")
#define BAR   do { FENCE; __builtin_amdgcn_s_barrier(); FENCE; } while (0)
#define DRAIN_LGKM asm volatile("s_waitcnt lgkmcnt(0)" ::: "memory")
#define WAIT_VM(N) asm volatile("s_waitcnt vmcnt(" #N ")" ::: "memory")

// ---------------- prep_all: x-transpose+cvt | wkv cvt | WqT ----------------
__global__ __launch_bounds__(256) void prep_all(const float* __restrict__ x,
                                                __hip_bfloat16* __restrict__ xt,
                                                const float* __restrict__ wqkv_f,
                                                __hip_bfloat16* __restrict__ wkv_b,
                                                __hip_bfloat16* __restrict__ wqT) {
    __shared__ float tile[64 * 133];
    int blk = blockIdx.x;
    int t = threadIdx.x;
    if (blk < 2048) {
        // transpose fp32 x[b][C][L] -> bf16 xt[b][L][C]; 64c x 128l tile
        int b = blk >> 8, rem = blk & 255;
        int l0 = (rem & 31) * 128, c0 = (rem >> 5) * 64;
        const float* xp = x + ((size_t)b * C_ + c0) * L_ + l0;
#pragma unroll
        for (int p = 0; p < 8; p++) {
            int i = p * 8 + (t >> 5);
            int j = (t & 31) * 4;
            float4 vv = *(const float4*)(xp + (size_t)i * L_ + j);
            *(float4*)&tile[i * 133 + j] = vv;
        }
        __syncthreads();
        unsigned short* xo = (unsigned short*)xt + ((size_t)b * L_ + l0) * C_ + c0;
        int cg8 = (t & 7) * 8;
#pragma unroll
        for (int qq = 0; qq < 4; qq++) {
            int l = qq * 32 + (t >> 3);
            bf16x8 ov;
#pragma unroll
            for (int k = 0; k < 8; k++) ov[k] = (__bf16)tile[(cg8 + k) * 133 + l];
            *(bf16x8*)(xo + (size_t)l * C_ + cg8) = ov;
        }
    } else if (blk < 4096) {
        int i = (blk - 2048) * 256 + t;  // 1024*512 elements (w_qkv rows 512..1535)
        wkv_b[i] = __float2bfloat16(wqkv_f[512 * 512 + i]);
    } else {
        // wqT[c][c'] = w_qkv[c'][c] (q-part rows 0..511), bf16
        int tb = blk - 4096;
        int r0 = (tb >> 4) * 32, c0 = (tb & 15) * 32;
        int tx = t & 31, ty = t >> 5;
        for (int r = 0; r < 32; r += 8)
            tile[(ty + r) * 33 + tx] = wqkv_f[(size_t)(r0 + ty + r) * 512 + c0 + tx];
        __syncthreads();
        for (int r = 0; r < 32; r += 8)
            wqT[(size_t)(c0 + ty + r) * 512 + r0 + tx] = __float2bfloat16(tile[tx * 33 + ty + r]);
    }
}

// ---------------- fused kv-GEMM + softmax-context (R8 loop/tail + R9 stores) ----------------
// Block (x=n-tile nt, y=head h, z=batch b): A-tile rows = {k[h*64..+63], v[h*64..+63]}
// (wkvb rows h*64+lr for lr<64; 448+h*64+lr for lr>=64), B-tile = xt n-slice.
// Main loop: R7/R8 2-phase counted-vmcnt pipeline (verified). Tail: P=exp(k) (wv0/1)
// + LDS row-sum accum; V (wv2/3); both bf16 to dead sA/sB (256B rows, grp g^(row&15));
// PV = P(64x128)@V^T in 16 MFMA/wave; PLAIN stores:
//   ctxp[nt][b*8+h][64][64], Sp[nt][b*8+h][64].
__global__ __launch_bounds__(256, 2) void gemm_kv(
    const __hip_bfloat16* __restrict__ A, const __hip_bfloat16* __restrict__ Bt,
    float* __restrict__ ctxp, float* __restrict__ Sp) {
    __shared__ alignas(16) unsigned short sA[2][128 * 64];  // 32 KiB
    __shared__ alignas(16) unsigned short sB[2][128 * 64];  // 32 KiB
    __shared__ float Sred[64];

    const int K = C_;
    int b = blockIdx.z, h = blockIdx.y, nt = blockIdx.x;
    int n0 = nt * 128;
    const __hip_bfloat16* Bb = Bt + (size_t)b * L_ * C_;

    int t = threadIdx.x;
    int lane = t & 63, wv = t >> 6;
    int l16 = lane & 15, q4 = lane >> 4;
    int wr = (wv >> 1) * 64, wc = (wv & 1) * 64;

    int srow = lane >> 3;
    int swz  = ((lane & 7) ^ srow) * 8;

    if (t < 64) Sred[t] = 0.f;

    const __hip_bfloat16* gA[4];
    const __hip_bfloat16* gB[4];
    unsigned ldoff[4];
#pragma unroll
    for (int c = 0; c < 4; c++) {
        int r = c * 32 + wv * 8;
        int lr = r + srow;                             // local row 0..127
        int grow = h * 64 + lr + (lr >= 64 ? 448 : 0); // k rows / v rows of head h
        gA[c] = A + (size_t)grow * K + swz;
        gB[c] = Bb + (size_t)(n0 + lr) * K + swz;
        ldoff[c] = (unsigned)r * 64;
    }

    int gsel0 = (q4 ^ (l16 & 7)) * 8;
    int gsel1 = gsel0 ^ 32;
    unsigned rA = (unsigned)(wr + l16) * 64;
    unsigned rB = (unsigned)(wc + l16) * 64;
    const int NKT = K >> 6;  // 8

    f32x4 acc[4][4] = {};
    bf16x8 aF[4][2], bF[4][2];

    // prologue: tile0 A+B, tile1 A; leave tile1 A (4) in flight
#pragma unroll
    for (int c = 0; c < 4; c++) GLD_LDS16(gA[c], &sA[0][ldoff[c]]);
#pragma unroll
    for (int c = 0; c < 4; c++) GLD_LDS16(gB[c], &sB[0][ldoff[c]]);
#pragma unroll
    for (int c = 0; c < 4; c++) GLD_LDS16(gA[c] + 64, &sA[1][ldoff[c]]);
    WAIT_VM(4);
    BAR;

#pragma unroll 1
    for (int kt = 0; kt < NKT; ++kt) {
        int cur = kt & 1, nbuf = cur ^ 1;
        const unsigned short* As_b = sA[cur];
        const unsigned short* Bs_b = sB[cur];
        bool st1 = (kt + 1) < NKT;
        bool st2 = (kt + 2) < NKT;

        // ---- phase 0: acc[0-3][0-1]; stage B(kt+1) -> other buf
#pragma unroll
        for (int i = 0; i < 4; i++) {
            aF[i][0] = *(const bf16x8*)&As_b[rA + i * 1024 + gsel0];
            aF[i][1] = *(const bf16x8*)&As_b[rA + i * 1024 + gsel1];
        }
#pragma unroll
        for (int j = 0; j < 2; j++) {
            bF[j][0] = *(const bf16x8*)&Bs_b[rB + j * 1024 + gsel0];
            bF[j][1] = *(const bf16x8*)&Bs_b[rB + j * 1024 + gsel1];
        }
        if (st1) {
            int ko = (kt + 1) << 6;
#pragma unroll
            for (int c = 0; c < 4; c++) GLD_LDS16(gB[c] + ko, &sB[nbuf][ldoff[c]]);
        }
        BAR;
        __builtin_amdgcn_s_setprio(1);
#pragma unroll
        for (int ks = 0; ks < 2; ks++)
#pragma unroll
            for (int i = 0; i < 4; i++)
#pragma unroll
                for (int j = 0; j < 2; j++)
                    acc[i][j] = __builtin_amdgcn_mfma_f32_16x16x32_bf16(aF[i][ks], bF[j][ks], acc[i][j], 0, 0, 0);
        __builtin_amdgcn_s_setprio(0);
        DRAIN_LGKM;
        BAR;

        // ---- phase 1: acc[0-3][2-3]; stage A(kt+2) into SAME buffer
#pragma unroll
        for (int j = 2; j < 4; j++) {
            bF[j][0] = *(const bf16x8*)&Bs_b[rB + j * 1024 + gsel0];
            bF[j][1] = *(const bf16x8*)&Bs_b[rB + j * 1024 + gsel1];
        }
        if (st2) {
            int ko = (kt + 2) << 6;
#pragma unroll
            for (int c = 0; c < 4; c++) GLD_LDS16(gA[c] + ko, &sA[cur][ldoff[c]]);
        }
        BAR;
        __builtin_amdgcn_s_setprio(1);
#pragma unroll
        for (int ks = 0; ks < 2; ks++)
#pragma unroll
            for (int i = 0; i < 4; i++)
#pragma unroll
                for (int j = 0; j < 2; j++)
                    acc[i][2 + j] = __builtin_amdgcn_mfma_f32_16x16x32_bf16(aF[i][ks], bF[2 + j][ks], acc[i][2 + j], 0, 0, 0);
        __builtin_amdgcn_s_setprio(0);
        DRAIN_LGKM;
        if (st2) { WAIT_VM(4); } else { WAIT_VM(0); }
        BAR;
    }
    // final BAR above: all staging + ds_reads complete; sA/sB reusable.

    // ---- fused tail: P = exp(k) -> sA, V -> sB (bf16, 256B rows, grp g^(row&15))
    __bf16* Pb = (__bf16*)sA;
    __bf16* Vb = (__bf16*)sB;

    if (wv < 2) {
        // k-half: exp, store P, row-sums into LDS (block-local)
#pragma unroll
        for (int i = 0; i < 4; i++)
#pragma unroll
            for (int r = 0; r < 4; r++) {
                int d = i * 16 + q4 * 4 + r;
                float rs = 0.f;
#pragma unroll
                for (int j = 0; j < 4; j++) {
                    int n = wc + j * 16 + l16;
                    float pv = __expf(acc[i][j][r]);
                    rs += pv;
                    Pb[d * 128 + (((n >> 3) ^ (d & 15)) * 8) + (n & 7)] = (__bf16)pv;
                }
                rs += __shfl_xor(rs, 1, 64);
                rs += __shfl_xor(rs, 2, 64);
                rs += __shfl_xor(rs, 4, 64);
                rs += __shfl_xor(rs, 8, 64);
                if (l16 == 0) atomicAdd(&Sred[d], rs);  // LDS atomic
            }
    } else {
        // v-half: store V
#pragma unroll
        for (int i = 0; i < 4; i++)
#pragma unroll
            for (int j = 0; j < 4; j++)
#pragma unroll
                for (int r = 0; r < 4; r++) {
                    int e = i * 16 + q4 * 4 + r;
                    int n = wc + j * 16 + l16;
                    Vb[e * 128 + (((n >> 3) ^ (e & 15)) * 8) + (n & 7)] = (__bf16)acc[i][j][r];
                }
    }
    DRAIN_LGKM;
    BAR;

    // ---- PV partial: Cp[d][e] = sum_{n<128} P[d][n] V[e][n]; wave -> e in [wv*16,+16)
    f32x4 acc2[4] = {};
#pragma unroll
    for (int kk = 0; kk < 4; kk++) {
        int gg = kk * 4 + q4;
        bf16x8 bf2 = *(const bf16x8*)&Vb[(wv * 16 + l16) * 128 + ((gg ^ l16) * 8)];
#pragma unroll
        for (int i2 = 0; i2 < 4; i2++) {
            bf16x8 af2 = *(const bf16x8*)&Pb[(i2 * 16 + l16) * 128 + ((gg ^ l16) * 8)];
            acc2[i2] = __builtin_amdgcn_mfma_f32_16x16x32_bf16(af2, bf2, acc2[i2], 0, 0, 0);
        }
    }

    // ---- epilogue: PLAIN stores (no global atomics)
    float* cg = ctxp + ((size_t)nt * 64 + b * 8 + h) * 4096;
#pragma unroll
    for (int i2 = 0; i2 < 4; i2++)
#pragma unroll
        for (int r = 0; r < 4; r++) {
            int d = i2 * 16 + q4 * 4 + r;
            int e = wv * 16 + l16;
            cg[d * 64 + e] = acc2[i2][r];
        }
    if (t < 64)
        Sp[((size_t)nt * 64 + b * 8 + h) * 64 + t] = Sred[t];
}

// ---------------- ctxred: ctxs[bh][4096] = sum over 32 slices of ctxp ----------------
__global__ __launch_bounds__(256) void ctxred(const float* __restrict__ ctxp,
                                              float* __restrict__ ctxs) {
    int q = blockIdx.x;   // 0..3 (quarter of 4096)
    int bh = blockIdx.y;  // 0..63
    int t = threadIdx.x;
    int i0 = q * 1024 + t * 4;
    const float* cg = ctxp + (size_t)bh * 4096 + i0;
    float4 s = {0.f, 0.f, 0.f, 0.f};
#pragma unroll
    for (int sl = 0; sl < 32; sl++) {
        float4 v = *(const float4*)(cg + (size_t)sl * 64 * 4096);
        s.x += v.x; s.y += v.y; s.z += v.z; s.w += v.w;
    }
    *(float4*)(ctxs + (size_t)bh * 4096 + i0) = s;
}

// ---------------- pipelined 128^2 GEMM, BK=64 (R11, verified) ----------------
// MODE 2: fp32 out + bias.  MODE 3: bf16 out.
template <int MODE>
__global__ __launch_bounds__(256, 2) void gemm_p(
    const __hip_bfloat16* __restrict__ A, const __hip_bfloat16* __restrict__ Bt,
    size_t strideA, size_t strideB, int M, int N, int K,
    __hip_bfloat16* __restrict__ obf,
    float* __restrict__ outb, const float* __restrict__ bias) {
    __shared__ alignas(16) unsigned short sA[2][128 * 64];
    __shared__ alignas(16) unsigned short sB[2][128 * 64];

    int b = blockIdx.z;
    int m0 = blockIdx.y * 128, n0 = blockIdx.x * 128;
    const __hip_bfloat16* Ab = A + strideA * (size_t)b;
    const __hip_bfloat16* Bb = Bt + strideB * (size_t)b;

    int t = threadIdx.x;
    int lane = t & 63, wv = t >> 6;
    int l16 = lane & 15, q4 = lane >> 4;
    int wr = (wv >> 1) * 64, wc = (wv & 1) * 64;

    int srow = lane >> 3;
    int swz  = ((lane & 7) ^ srow) * 8;

    const __hip_bfloat16* gA[4];
    const __hip_bfloat16* gB[4];
    unsigned ldoff[4];
#pragma unroll
    for (int c = 0; c < 4; c++) {
        int r = c * 32 + wv * 8;
        gA[c] = Ab + (size_t)(m0 + r + srow) * K + swz;
        gB[c] = Bb + (size_t)(n0 + r + srow) * K + swz;
        ldoff[c] = (unsigned)r * 64;
    }

    int gsel0 = (q4 ^ (l16 & 7)) * 8;
    int gsel1 = gsel0 ^ 32;
    unsigned rA = (unsigned)(wr + l16) * 64;
    unsigned rB = (unsigned)(wc + l16) * 64;
    int NKT = K >> 6;

    f32x4 acc[4][4] = {};
    bf16x8 aF[4][2], bF[4][2];

#pragma unroll
    for (int c = 0; c < 4; c++) GLD_LDS16(gA[c], &sA[0][ldoff[c]]);
#pragma unroll
    for (int c = 0; c < 4; c++) GLD_LDS16(gB[c], &sB[0][ldoff[c]]);
    if (NKT > 1) {
#pragma unroll
        for (int c = 0; c < 4; c++) GLD_LDS16(gA[c] + 64, &sA[1][ldoff[c]]);
        WAIT_VM(4);
    } else {
        WAIT_VM(0);
    }
    BAR;

#pragma unroll 1
    for (int kt = 0; kt < NKT; ++kt) {
        int cur = kt & 1, nbuf = cur ^ 1;
        const unsigned short* As_b = sA[cur];
        const unsigned short* Bs_b = sB[cur];
        bool st1 = (kt + 1) < NKT;
        bool st2 = (kt + 2) < NKT;

#pragma unroll
        for (int i = 0; i < 4; i++) {
            aF[i][0] = *(const bf16x8*)&As_b[rA + i * 1024 + gsel0];
            aF[i][1] = *(const bf16x8*)&As_b[rA + i * 1024 + gsel1];
        }
#pragma unroll
        for (int j = 0; j < 2; j++) {
            bF[j][0] = *(const bf16x8*)&Bs_b[rB + j * 1024 + gsel0];
            bF[j][1] = *(const bf16x8*)&Bs_b[rB + j * 1024 + gsel1];
        }
        if (st1) {
            int ko = (kt + 1) << 6;
#pragma unroll
            for (int c = 0; c < 4; c++) GLD_LDS16(gB[c] + ko, &sB[nbuf][ldoff[c]]);
        }
        BAR;
        __builtin_amdgcn_s_setprio(1);
#pragma unroll
        for (int ks = 0; ks < 2; ks++)
#pragma unroll
            for (int i = 0; i < 4; i++)
#pragma unroll
                for (int j = 0; j < 2; j++)
                    acc[i][j] = __builtin_amdgcn_mfma_f32_16x16x32_bf16(aF[i][ks], bF[j][ks], acc[i][j], 0, 0, 0);
        __builtin_amdgcn_s_setprio(0);
        DRAIN_LGKM;
        BAR;

#pragma unroll
        for (int j = 2; j < 4; j++) {
            bF[j][0] = *(const bf16x8*)&Bs_b[rB + j * 1024 + gsel0];
            bF[j][1] = *(const bf16x8*)&Bs_b[rB + j * 1024 + gsel1];
        }
        if (st2) {
            int ko = (kt + 2) << 6;
#pragma unroll
            for (int c = 0; c < 4; c++) GLD_LDS16(gA[c] + ko, &sA[cur][ldoff[c]]);
        }
        BAR;
        __builtin_amdgcn_s_setprio(1);
#pragma unroll
        for (int ks = 0; ks < 2; ks++)
#pragma unroll
            for (int i = 0; i < 4; i++)
#pragma unroll
                for (int j = 0; j < 2; j++)
                    acc[i][2 + j] = __builtin_amdgcn_mfma_f32_16x16x32_bf16(aF[i][ks], bF[2 + j][ks], acc[i][2 + j], 0, 0, 0);
        __builtin_amdgcn_s_setprio(0);
        DRAIN_LGKM;
        if (st2) { WAIT_VM(4); } else { WAIT_VM(0); }
        BAR;
    }

#pragma unroll
    for (int i = 0; i < 4; i++)
#pragma unroll
        for (int j = 0; j < 4; j++)
#pragma unroll
            for (int r = 0; r < 4; r++) {
                int row = m0 + wr + i * 16 + q4 * 4 + r;
                int col = n0 + wc + j * 16 + l16;
                float val = acc[i][j][r];
                if (MODE == 3) {
                    obf[((size_t)b * 512 + row) * (size_t)N + col] = __float2bfloat16(val);
                } else {
                    outb[((size_t)b * M + row) * (size_t)N + col] = val + bias[row];
                }
            }
}

// ---------------- w2[b][o][h*64+d] = sum_e w_out[o][h*64+e] * ctxs[d][e]/S[d] ----------------
__global__ __launch_bounds__(256) void w2_kernel(const float* __restrict__ wout,
                                                 const float* __restrict__ ctxs,
                                                 const float* __restrict__ Sp,
                                                 __hip_bfloat16* __restrict__ w2) {
    int ob = blockIdx.x, h = blockIdx.y, b = blockIdx.z;
    __shared__ float cT[64 * 65];  // [e][d], pre-scaled by 1/S[d]
    __shared__ float wT[64 * 65];  // [e][ol]
    __shared__ float Sinv[64];
    int t = threadIdx.x;
    const float* cg = ctxs + ((size_t)b * 8 + h) * 4096;
    if (t < 64) {
        const float* sg = Sp + ((size_t)b * 8 + h) * 64;
        float S = 0.f;
#pragma unroll
        for (int s = 0; s < 32; s++) S += sg[(size_t)s * 64 * 64 + t];
        Sinv[t] = 1.0f / S;
    }
    __syncthreads();
#pragma unroll
    for (int it = 0; it < 4; ++it) {
        int i0 = (t + it * 256) * 4;
        int d = i0 >> 6, e0 = i0 & 63;
        float4 s4 = *(const float4*)&cg[i0];
        float si = Sinv[d];
        float4 wv4 = *(const float4*)&wout[(size_t)(ob * 64 + d) * 512 + h * 64 + e0];
        cT[(e0 + 0) * 65 + d] = s4.x * si;
        cT[(e0 + 1) * 65 + d] = s4.y * si;
        cT[(e0 + 2) * 65 + d] = s4.z * si;
        cT[(e0 + 3) * 65 + d] = s4.w * si;
        wT[(e0 + 0) * 65 + d] = wv4.x;
        wT[(e0 + 1) * 65 + d] = wv4.y;
        wT[(e0 + 2) * 65 + d] = wv4.z;
        wT[(e0 + 3) * 65 + d] = wv4.w;
    }
    __syncthreads();
    int ol = t >> 2;
    int db = (t & 3) * 16;
    unsigned short* w2p = (unsigned short*)w2 + ((size_t)b * 512 + ob * 64 + ol) * 512 + h * 64;
    for (int g = 0; g < 4; g++) {
        int d0 = db + g * 4;
        float s0 = 0.f, s1 = 0.f, s2 = 0.f, s3 = 0.f;
#pragma unroll
        for (int e = 0; e < 64; e++) {
            float w = wT[e * 65 + ol];
            s0 += w * cT[e * 65 + d0];
            s1 += w * cT[e * 65 + d0 + 1];
            s2 += w * cT[e * 65 + d0 + 2];
            s3 += w * cT[e * 65 + d0 + 3];
        }
        bf16x4 ov;
        ov[0] = (__bf16)s0; ov[1] = (__bf16)s1; ov[2] = (__bf16)s2; ov[3] = (__bf16)s3;
        *(bf16x4*)(w2p + d0) = ov;
    }
}

// ---------------- launch ----------------
extern "C" void kernel_launch(void* const* d_in, const int* in_sizes, int n_in,
                              void* d_out, int out_size, void* d_ws, size_t ws_size,
                              hipStream_t stream) {
    const float* x     = (const float*)d_in[0];
    const float* w_qkv = (const float*)d_in[1];
    const float* w_out = (const float*)d_in[2];
    const float* b_out = (const float*)d_in[3];
    float* out = (float*)d_out;
    char* ws = (char*)d_ws;

    size_t off_xt   = 0;                                       // bf16 [b][L][C]  32 MiB
    size_t off_wkv  = off_xt + (size_t)B_ * L_ * C_ * 2;       // bf16 1024x512    1 MiB
    size_t off_wqT  = off_wkv + (size_t)1024 * 512 * 2;        // bf16 512x512   0.5 MiB
    size_t off_ctxp = off_wqT + (size_t)512 * 512 * 2;         // fp32 32sl*64bh*4096  32 MiB
    size_t off_Sp   = off_ctxp + (size_t)32 * 64 * 4096 * 4;   // fp32 32sl*64bh*64  512 KiB
    size_t off_ctxs = off_Sp + (size_t)32 * 64 * 64 * 4;       // fp32 64bh*4096    1 MiB
    size_t off_w2   = off_ctxs + (size_t)64 * 4096 * 4;        // bf16 8x512x512    4 MiB
    size_t off_w3   = off_w2 + (size_t)B_ * 512 * 512 * 2;     // bf16              4 MiB

    __hip_bfloat16* xt   = (__hip_bfloat16*)(ws + off_xt);
    __hip_bfloat16* wkvb = (__hip_bfloat16*)(ws + off_wkv);
    __hip_bfloat16* wqT  = (__hip_bfloat16*)(ws + off_wqT);
    float*          ctxp = (float*)(ws + off_ctxp);
    float*          Sp   = (float*)(ws + off_Sp);
    float*          ctxs = (float*)(ws + off_ctxs);
    __hip_bfloat16* w2   = (__hip_bfloat16*)(ws + off_w2);
    __hip_bfloat16* W3   = (__hip_bfloat16*)(ws + off_w3);

    prep_all<<<4352, 256, 0, stream>>>(x, xt, w_qkv, wkvb, wqT);

    // fused: per (n-tile, head, batch) K-loop + exp/rowsum + P@V^T -> plain partials
    gemm_kv<<<dim3(L_ / 128, 8, B_), 256, 0, stream>>>(wkvb, xt, ctxp, Sp);

    // sum 32 slices -> ctxs
    ctxred<<<dim3(4, 64), 256, 0, stream>>>(ctxp, ctxs);

    w2_kernel<<<dim3(8, 8, B_), 256, 0, stream>>>(w_out, ctxs, Sp, w2);

    // W3[b] = w2[b] @ Wq   (M=512, N=512, K=512) — bf16 out
    gemm_p<3><<<dim3(512 / 128, 512 / 128, B_), 256, 0, stream>>>(
        w2, wqT, (size_t)512 * 512, 0, 512, 512, 512, W3, nullptr, nullptr);

    // out = W3[b] @ x[b] + b_out   (M=512, N=4096, K=512)
    gemm_p<2><<<dim3(L_ / 128, 512 / 128, B_), 256, 0, stream>>>(
        W3, xt, (size_t)512 * 512, (size_t)L_ * C_, 512, L_, 512, nullptr, out, b_out);
}